// Round 1
// baseline (908.749 us; speedup 1.0000x reference)
//
#include <hip/hip_runtime.h>
#include <hip/hip_bf16.h>
#include <stdint.h>
#include <stddef.h>

// Problem dims (fixed by reference)
#define BSZ  8192
#define DIN  1024
#define HH   4096
#define DOUT 1024

// GEMM tile config (m93/m97 recipe: 128x128 tile, BK=32, 16x16x32 bf16 MFMA)
#define BM 128
#define BN 128
#define BK 32

typedef __attribute__((ext_vector_type(8))) short   frag8;   // 8 bf16 (4 VGPRs)
typedef __attribute__((ext_vector_type(4))) float   f32x4;   // MFMA C/D
typedef __attribute__((ext_vector_type(4))) float   float4v;
typedef __attribute__((ext_vector_type(8))) unsigned short u16x8;

__device__ __forceinline__ unsigned short f2bf_rne(float f) {
    union { float f; uint32_t u; } c; c.f = f;
    uint32_t u = c.u;
    return (unsigned short)((u + 0x7FFFu + ((u >> 16) & 1u)) >> 16);
}

// f32 -> bf16 (RNE), 8 elems/thread, vectorized
__global__ __launch_bounds__(256)
void cvt_f32_bf16(const float* __restrict__ src, unsigned short* __restrict__ dst, long n) {
    long i = ((long)blockIdx.x * blockDim.x + threadIdx.x) * 8;
    if (i >= n) return;
    float4v v0 = *(const float4v*)(src + i);
    float4v v1 = *(const float4v*)(src + i + 4);
    u16x8 o;
    o[0] = f2bf_rne(v0[0]); o[1] = f2bf_rne(v0[1]); o[2] = f2bf_rne(v0[2]); o[3] = f2bf_rne(v0[3]);
    o[4] = f2bf_rne(v1[0]); o[5] = f2bf_rne(v1[1]); o[6] = f2bf_rne(v1[2]); o[7] = f2bf_rne(v1[3]);
    *(u16x8*)(dst + i) = o;
}

// Stage one 128x32 tile (A or B operand, both K-major / B^T form) into LDS.
// Thread t covers LDS bytes [t*16, t*16+16) per half => matches global_load_lds
// wave-uniform-base + lane*16 requirement (no padding).
template <bool BF16SRC>
__device__ __forceinline__ void stage_tile(const void* __restrict__ src, int ld,
                                           int tile_row, int kk,
                                           short* __restrict__ dst, int tid) {
    const int sr = tid >> 2;          // row within half (0..63)
    const int sc = (tid & 3) * 8;     // k-col (0,8,16,24)
    if (BF16SRC) {
        const unsigned short* s = (const unsigned short*)src;
#pragma unroll
        for (int h = 0; h < 2; h++) {
            const unsigned short* gp = s + (size_t)(tile_row + sr + h * 64) * ld + kk + sc;
            __builtin_amdgcn_global_load_lds(
                (const __attribute__((address_space(1))) uint32_t*)gp,
                (__attribute__((address_space(3))) uint32_t*)&dst[(h * 256 + tid) * 8],
                16, 0, 0);
        }
    } else {
        const float* s = (const float*)src;
#pragma unroll
        for (int h = 0; h < 2; h++) {
            const float* gp = s + (size_t)(tile_row + sr + h * 64) * ld + kk + sc;
            float4v v0 = *(const float4v*)gp;
            float4v v1 = *(const float4v*)(gp + 4);
            u16x8 o;
            o[0] = f2bf_rne(v0[0]); o[1] = f2bf_rne(v0[1]); o[2] = f2bf_rne(v0[2]); o[3] = f2bf_rne(v0[3]);
            o[4] = f2bf_rne(v1[0]); o[5] = f2bf_rne(v1[1]); o[6] = f2bf_rne(v1[2]); o[7] = f2bf_rne(v1[3]);
            *(u16x8*)&dst[(h * 256 + tid) * 8] = o;
        }
    }
}

// C[m,n] = relu( sum_k A[m,k]*B[n,k] + bias1[n] (+ bias2[n]) )
// A has two K-regions: k < Ksplit -> (A1,lda1), else (A2,lda2,k-Ksplit). Same for B.
// Writes f32 C; optionally bf16 copy Cb (for feeding the next GEMM).
template <bool A_BF16, bool B_BF16>
__global__ __launch_bounds__(256)
void gemm_bt_relu(const void* __restrict__ A1, int lda1,
                  const void* __restrict__ A2, int lda2,
                  const void* __restrict__ B1, int ldb1,
                  const void* __restrict__ B2, int ldb2,
                  int Ksplit, int K,
                  const float* __restrict__ bias1, const float* __restrict__ bias2,
                  float* __restrict__ C, unsigned short* __restrict__ Cb, int N) {
    __shared__ short As[BM * BK];
    __shared__ short Bs[BN * BK];

    const int tid    = threadIdx.x;
    const int tile_m = blockIdx.y * BM;
    const int tile_n = blockIdx.x * BN;
    const int wave = tid >> 6, lane = tid & 63;
    const int quad = lane >> 4, l16 = lane & 15;
    const int wm = (wave >> 1) * 64;   // wave's 64x64 sub-tile
    const int wn = (wave & 1) * 64;

    f32x4 acc[4][4] = {};

    for (int kofs = 0; kofs < K; kofs += BK) {
        __syncthreads();
        if (kofs < Ksplit) {
            stage_tile<A_BF16>(A1, lda1, tile_m, kofs, As, tid);
            stage_tile<B_BF16>(B1, ldb1, tile_n, kofs, Bs, tid);
        } else {
            stage_tile<A_BF16>(A2, lda2, tile_m, kofs - Ksplit, As, tid);
            stage_tile<B_BF16>(B2, ldb2, tile_n, kofs - Ksplit, Bs, tid);
        }
        __syncthreads();

        frag8 af[4], bf[4];
#pragma unroll
        for (int i = 0; i < 4; i++)
            af[i] = *(const frag8*)&As[(wm + i * 16 + l16) * BK + quad * 8];
#pragma unroll
        for (int i = 0; i < 4; i++)
            bf[i] = *(const frag8*)&Bs[(wn + i * 16 + l16) * BK + quad * 8];
#pragma unroll
        for (int mi = 0; mi < 4; mi++)
#pragma unroll
            for (int ni = 0; ni < 4; ni++)
                acc[mi][ni] = __builtin_amdgcn_mfma_f32_16x16x32_bf16(
                    af[mi], bf[ni], acc[mi][ni], 0, 0, 0);
    }

    // Epilogue: C/D layout (verified m89/m91): n = lane&15, m = quad*4 + reg
#pragma unroll
    for (int mi = 0; mi < 4; mi++) {
        const int m0 = tile_m + wm + mi * 16 + quad * 4;
#pragma unroll
        for (int ni = 0; ni < 4; ni++) {
            const int n = tile_n + wn + ni * 16 + l16;
            float bv = bias1[n];
            if (bias2) bv += bias2[n];
#pragma unroll
            for (int r = 0; r < 4; r++) {
                float v = acc[mi][ni][r] + bv;
                v = v > 0.f ? v : 0.f;
                const size_t idx = (size_t)(m0 + r) * N + n;
                C[idx] = v;
                if (Cb) Cb[idx] = f2bf_rne(v);
            }
        }
    }
}

extern "C" void kernel_launch(void* const* d_in, const int* in_sizes, int n_in,
                              void* d_out, int out_size, void* d_ws, size_t ws_size,
                              hipStream_t stream) {
    const float* X     = (const float*)d_in[0];
    const float* state = (const float*)d_in[1];
    const float* W_in  = (const float*)d_in[2];
    const float* b_in  = (const float*)d_in[3];
    const float* W_rec = (const float*)d_in[4];
    const float* b_rec = (const float*)d_in[5];
    const float* W_out = (const float*)d_in[6];
    const float* b_out = (const float*)d_in[7];

    float* out       = (float*)d_out;                       // [8192,1024]
    float* new_state = out + (size_t)BSZ * DOUT;            // [8192,4096]

    const size_t nX = (size_t)BSZ * DIN, nS = (size_t)BSZ * HH;
    const size_t nWin = (size_t)HH * DIN, nWrec = (size_t)HH * HH, nWout = (size_t)DOUT * HH;

    // Full-fast-path ws layout (all bf16): X | state | W_in | W_rec | W_out | new_state
    const size_t offX = 0;
    const size_t offS = offX + nX * 2;
    const size_t offWin = offS + nS * 2;
    const size_t offWrec = offWin + nWin * 2;
    const size_t offWout = offWrec + nWrec * 2;
    const size_t offNS = offWout + nWout * 2;
    const size_t need_full = offNS + nS * 2;                 // ~192 MiB
    const size_t need_mid = nS * 2 + nWout * 2;              // NSb + Woutb (~72 MiB)

    char* ws = (char*)d_ws;
    const dim3 blk(256);
    const dim3 g1(HH / BN, BSZ / BM);     // kernel1: [8192 x 4096]
    const dim3 g2(DOUT / BN, BSZ / BM);   // kernel2: [8192 x 1024]

    auto cvt = [&](const float* s, unsigned short* d, size_t n) {
        int threads = (int)(n / 8);
        cvt_f32_bf16<<<dim3((threads + 255) / 256), blk, 0, stream>>>(s, d, (long)n);
    };

    if (ws_size >= need_full) {
        unsigned short* Xb = (unsigned short*)(ws + offX);
        unsigned short* Sb = (unsigned short*)(ws + offS);
        unsigned short* Winb = (unsigned short*)(ws + offWin);
        unsigned short* Wrecb = (unsigned short*)(ws + offWrec);
        unsigned short* Woutb = (unsigned short*)(ws + offWout);
        unsigned short* NSb = (unsigned short*)(ws + offNS);
        cvt(X, Xb, nX);
        cvt(state, Sb, nS);
        cvt(W_in, Winb, nWin);
        cvt(W_rec, Wrecb, nWrec);
        cvt(W_out, Woutb, nWout);
        gemm_bt_relu<true, true><<<g1, blk, 0, stream>>>(
            Xb, DIN, Sb, HH, Winb, DIN, Wrecb, HH, DIN, DIN + HH,
            b_in, b_rec, new_state, NSb, HH);
        gemm_bt_relu<true, true><<<g2, blk, 0, stream>>>(
            NSb, HH, NSb, HH, Woutb, HH, Woutb, HH, HH, HH,
            b_out, nullptr, out, nullptr, DOUT);
    } else if (ws_size >= need_mid) {
        unsigned short* NSb = (unsigned short*)ws;
        unsigned short* Woutb = (unsigned short*)(ws + nS * 2);
        cvt(W_out, Woutb, nWout);
        gemm_bt_relu<false, false><<<g1, blk, 0, stream>>>(
            X, DIN, state, HH, W_in, DIN, W_rec, HH, DIN, DIN + HH,
            b_in, b_rec, new_state, NSb, HH);
        gemm_bt_relu<true, true><<<g2, blk, 0, stream>>>(
            NSb, HH, NSb, HH, Woutb, HH, Woutb, HH, HH, HH,
            b_out, nullptr, out, nullptr, DOUT);
    } else {
        // No-ws fallback: inline f32->bf16 staging everywhere; kernel2 reads
        // the f32 new_state from d_out.
        gemm_bt_relu<false, false><<<g1, blk, 0, stream>>>(
            X, DIN, state, HH, W_in, DIN, W_rec, HH, DIN, DIN + HH,
            b_in, b_rec, new_state, nullptr, HH);
        gemm_bt_relu<false, false><<<g2, blk, 0, stream>>>(
            new_state, HH, new_state, HH, W_out, HH, W_out, HH, HH, HH,
            b_out, nullptr, out, nullptr, DOUT);
    }
}

// Round 2
// 897.152 us; speedup vs baseline: 1.0129x; 1.0129x over previous
//
#include <hip/hip_runtime.h>
#include <hip/hip_bf16.h>
#include <stdint.h>
#include <stddef.h>

// Problem dims (fixed by reference)
#define BSZ  8192
#define DIN  1024
#define HH   4096
#define DOUT 1024

// GEMM tile config (m93/m97 recipe: 128x128 tile, BK=32, 16x16x32 bf16 MFMA)
#define BM 128
#define BN 128
#define BK 32

typedef __attribute__((ext_vector_type(8))) short   frag8;   // 8 bf16 (4 VGPRs)
typedef __attribute__((ext_vector_type(4))) float   f32x4;   // MFMA C/D
typedef __attribute__((ext_vector_type(8))) unsigned short u16x8;

__device__ __forceinline__ unsigned short f2bf_rne(float f) {
    union { float f; uint32_t u; } c; c.f = f;
    uint32_t u = c.u;
    return (unsigned short)((u + 0x7FFFu + ((u >> 16) & 1u)) >> 16);
}

__device__ __forceinline__ void cvt8(const float* __restrict__ s, unsigned short* __restrict__ d) {
    f32x4 v0 = *(const f32x4*)s;
    f32x4 v1 = *(const f32x4*)(s + 4);
    u16x8 o;
    o[0] = f2bf_rne(v0[0]); o[1] = f2bf_rne(v0[1]); o[2] = f2bf_rne(v0[2]); o[3] = f2bf_rne(v0[3]);
    o[4] = f2bf_rne(v1[0]); o[5] = f2bf_rne(v1[1]); o[6] = f2bf_rne(v1[2]); o[7] = f2bf_rne(v1[3]);
    *(u16x8*)d = o;
}

// Single-array f32->bf16 (used by mid-ws fallback only)
__global__ __launch_bounds__(256)
void cvt_f32_bf16(const float* __restrict__ src, unsigned short* __restrict__ dst, long n) {
    long i = ((long)blockIdx.x * 256 + threadIdx.x) * 8;
    if (i < n) cvt8(src + i, dst + i);
}

// All five input arrays converted in ONE dispatch (saves 4 launch/tail overheads)
__global__ __launch_bounds__(256)
void cvt_all5(const float* __restrict__ s0, unsigned short* __restrict__ d0, long n0,
              const float* __restrict__ s1, unsigned short* __restrict__ d1, long n1,
              const float* __restrict__ s2, unsigned short* __restrict__ d2, long n2,
              const float* __restrict__ s3, unsigned short* __restrict__ d3, long n3,
              const float* __restrict__ s4, unsigned short* __restrict__ d4, long n4) {
    long i = ((long)blockIdx.x * 256 + threadIdx.x) * 8;
    if (i < n0) { cvt8(s0 + i, d0 + i); return; } i -= n0;
    if (i < n1) { cvt8(s1 + i, d1 + i); return; } i -= n1;
    if (i < n2) { cvt8(s2 + i, d2 + i); return; } i -= n2;
    if (i < n3) { cvt8(s3 + i, d3 + i); return; } i -= n3;
    if (i < n4) { cvt8(s4 + i, d4 + i); }
}

__device__ __forceinline__ void glds16(const unsigned short* __restrict__ gp, short* lp) {
    __builtin_amdgcn_global_load_lds(
        (const __attribute__((address_space(1))) uint32_t*)gp,
        (__attribute__((address_space(3))) uint32_t*)lp, 16, 0, 0);
}

// C[m,n] = relu( sum_k A[m,k]*B[n,k] + bias1[n] (+ bias2[n]) )
// Two K-regions (split concat GEMM): phase 0 = (A1,B1,k<Ksplit), phase 1 = (A2,B2).
// Branch hoisted OUT of the hot loop; staging uses incremented per-thread pointers.
template <bool A_BF16, bool B_BF16>
__global__ __launch_bounds__(256)
void gemm_bt_relu(const void* __restrict__ A1, int lda1,
                  const void* __restrict__ A2, int lda2,
                  const void* __restrict__ B1, int ldb1,
                  const void* __restrict__ B2, int ldb2,
                  int Ksplit, int K,
                  const float* __restrict__ bias1, const float* __restrict__ bias2,
                  float* __restrict__ C, unsigned short* __restrict__ Cb, int N) {
    __shared__ short As[BM * BK];
    __shared__ short Bs[BN * BK];

    const int tid    = threadIdx.x;
    const int tile_m = blockIdx.y * BM;
    const int tile_n = blockIdx.x * BN;
    const int wave = tid >> 6, lane = tid & 63;
    const int quad = lane >> 4, l16 = lane & 15;
    const int wm = (wave >> 1) * 64;   // wave's 64x64 sub-tile
    const int wn = (wave & 1) * 64;
    const int sr = tid >> 2;           // staging row within half (0..63)
    const int sc = (tid & 3) * 8;      // staging k-col (0,8,16,24)

    // global_load_lds LDS dst is wave-uniform base + lane*16 -> tid*8 shorts
    short* ldsA0 = &As[tid * 8]; short* ldsA1 = &As[(256 + tid) * 8];
    short* ldsB0 = &Bs[tid * 8]; short* ldsB1 = &Bs[(256 + tid) * 8];

    f32x4 acc[4][4] = {};

    for (int phase = 0; phase < 2; ++phase) {
        const int kmax = phase ? (K - Ksplit) : Ksplit;
        if (kmax <= 0) continue;
        const void* Ap = phase ? A2 : A1; const int la = phase ? lda2 : lda1;
        const void* Bp = phase ? B2 : B1; const int lb = phase ? ldb2 : ldb1;

        const unsigned short *ga = nullptr, *gb = nullptr;
        const float *fa = nullptr, *fb = nullptr;
        if (A_BF16) ga = (const unsigned short*)Ap + (size_t)(tile_m + sr) * la + sc;
        else        fa = (const float*)Ap          + (size_t)(tile_m + sr) * la + sc;
        if (B_BF16) gb = (const unsigned short*)Bp + (size_t)(tile_n + sr) * lb + sc;
        else        fb = (const float*)Bp          + (size_t)(tile_n + sr) * lb + sc;
        const size_t la64 = (size_t)64 * la, lb64 = (size_t)64 * lb;

        for (int kk = 0; kk < kmax; kk += BK) {
            __syncthreads();
            if (A_BF16) {
                glds16(ga, ldsA0); glds16(ga + la64, ldsA1); ga += BK;
            } else {
                unsigned short t0[8], t1[8];
                cvt8(fa, t0); cvt8(fa + la64, t1); fa += BK;
                *(u16x8*)ldsA0 = *(u16x8*)t0; *(u16x8*)ldsA1 = *(u16x8*)t1;
            }
            if (B_BF16) {
                glds16(gb, ldsB0); glds16(gb + lb64, ldsB1); gb += BK;
            } else {
                unsigned short t0[8], t1[8];
                cvt8(fb, t0); cvt8(fb + lb64, t1); fb += BK;
                *(u16x8*)ldsB0 = *(u16x8*)t0; *(u16x8*)ldsB1 = *(u16x8*)t1;
            }
            __syncthreads();

            frag8 af[4], bfr[4];
#pragma unroll
            for (int i = 0; i < 4; i++)
                af[i] = *(const frag8*)&As[(wm + i * 16 + l16) * BK + quad * 8];
#pragma unroll
            for (int i = 0; i < 4; i++)
                bfr[i] = *(const frag8*)&Bs[(wn + i * 16 + l16) * BK + quad * 8];
#pragma unroll
            for (int mi = 0; mi < 4; mi++)
#pragma unroll
                for (int ni = 0; ni < 4; ni++)
                    acc[mi][ni] = __builtin_amdgcn_mfma_f32_16x16x32_bf16(
                        af[mi], bfr[ni], acc[mi][ni], 0, 0, 0);
        }
    }

    // Epilogue: C/D layout (verified m89/m91): n = lane&15, m = quad*4 + reg
#pragma unroll
    for (int mi = 0; mi < 4; mi++) {
        const int m0 = tile_m + wm + mi * 16 + quad * 4;
#pragma unroll
        for (int ni = 0; ni < 4; ni++) {
            const int n = tile_n + wn + ni * 16 + l16;
            float bv = bias1[n];
            if (bias2) bv += bias2[n];
#pragma unroll
            for (int r = 0; r < 4; r++) {
                float v = acc[mi][ni][r] + bv;
                v = v > 0.f ? v : 0.f;
                const size_t idx = (size_t)(m0 + r) * N + n;
                C[idx] = v;
                if (Cb) Cb[idx] = f2bf_rne(v);
            }
        }
    }
}

extern "C" void kernel_launch(void* const* d_in, const int* in_sizes, int n_in,
                              void* d_out, int out_size, void* d_ws, size_t ws_size,
                              hipStream_t stream) {
    const float* X     = (const float*)d_in[0];
    const float* state = (const float*)d_in[1];
    const float* W_in  = (const float*)d_in[2];
    const float* b_in  = (const float*)d_in[3];
    const float* W_rec = (const float*)d_in[4];
    const float* b_rec = (const float*)d_in[5];
    const float* W_out = (const float*)d_in[6];
    const float* b_out = (const float*)d_in[7];

    float* out       = (float*)d_out;                       // [8192,1024]
    float* new_state = out + (size_t)BSZ * DOUT;            // [8192,4096]

    const size_t nX = (size_t)BSZ * DIN, nS = (size_t)BSZ * HH;
    const size_t nWin = (size_t)HH * DIN, nWrec = (size_t)HH * HH, nWout = (size_t)DOUT * HH;

    // Full-fast-path ws layout (all bf16): X | state | W_in | W_rec | W_out | new_state
    const size_t offX = 0;
    const size_t offS = offX + nX * 2;
    const size_t offWin = offS + nS * 2;
    const size_t offWrec = offWin + nWin * 2;
    const size_t offWout = offWrec + nWrec * 2;
    const size_t offNS = offWout + nWout * 2;
    const size_t need_full = offNS + nS * 2;                 // ~192 MiB
    const size_t need_mid = nS * 2 + nWout * 2;              // NSb + Woutb (~72 MiB)

    char* ws = (char*)d_ws;
    const dim3 blk(256);
    const dim3 g1(HH / BN, BSZ / BM);     // kernel1: [8192 x 4096]
    const dim3 g2(DOUT / BN, BSZ / BM);   // kernel2: [8192 x 1024]

    if (ws_size >= need_full) {
        unsigned short* Xb    = (unsigned short*)(ws + offX);
        unsigned short* Sb    = (unsigned short*)(ws + offS);
        unsigned short* Winb  = (unsigned short*)(ws + offWin);
        unsigned short* Wrecb = (unsigned short*)(ws + offWrec);
        unsigned short* Woutb = (unsigned short*)(ws + offWout);
        unsigned short* NSb   = (unsigned short*)(ws + offNS);
        const long total = (long)(nX + nS + nWin + nWrec + nWout);
        cvt_all5<<<dim3((unsigned)((total / 8 + 255) / 256)), blk, 0, stream>>>(
            X, Xb, (long)nX, state, Sb, (long)nS, W_in, Winb, (long)nWin,
            W_rec, Wrecb, (long)nWrec, W_out, Woutb, (long)nWout);
        gemm_bt_relu<true, true><<<g1, blk, 0, stream>>>(
            Xb, DIN, Sb, HH, Winb, DIN, Wrecb, HH, DIN, DIN + HH,
            b_in, b_rec, new_state, NSb, HH);
        gemm_bt_relu<true, true><<<g2, blk, 0, stream>>>(
            NSb, HH, NSb, HH, Woutb, HH, Woutb, HH, HH, HH,
            b_out, nullptr, out, nullptr, DOUT);
    } else if (ws_size >= need_mid) {
        unsigned short* NSb   = (unsigned short*)ws;
        unsigned short* Woutb = (unsigned short*)(ws + nS * 2);
        cvt_f32_bf16<<<dim3((unsigned)((nWout / 8 + 255) / 256)), blk, 0, stream>>>(
            W_out, Woutb, (long)nWout);
        gemm_bt_relu<false, false><<<g1, blk, 0, stream>>>(
            X, DIN, state, HH, W_in, DIN, W_rec, HH, DIN, DIN + HH,
            b_in, b_rec, new_state, NSb, HH);
        gemm_bt_relu<true, true><<<g2, blk, 0, stream>>>(
            NSb, HH, NSb, HH, Woutb, HH, Woutb, HH, HH, HH,
            b_out, nullptr, out, nullptr, DOUT);
    } else {
        // No-ws fallback: inline f32->bf16 staging; kernel2 reads f32 new_state.
        gemm_bt_relu<false, false><<<g1, blk, 0, stream>>>(
            X, DIN, state, HH, W_in, DIN, W_rec, HH, DIN, DIN + HH,
            b_in, b_rec, new_state, nullptr, HH);
        gemm_bt_relu<false, false><<<g2, blk, 0, stream>>>(
            new_state, HH, new_state, HH, W_out, HH, W_out, HH, HH, HH,
            b_out, nullptr, out, nullptr, DOUT);
    }
}